// Round 1
// baseline (2608.773 us; speedup 1.0000x reference)
//
#include <hip/hip_runtime.h>
#include <math.h>

#define TOKENS   32768
#define DMODEL   2048
#define DHID     1024
#define NEXP     16
#define BM       64
#define BK       64
#define BN       64
#define XS_LD    68   // padded leading dim for xs/hs (68*4B: 16B-aligned rows, bank-spread)
#define HS_LD    68

// Output layout (floats): gates[TOKENS*2] | indices[TOKENS*2] | probs[TOKENS*16]
#define OFF_IDX   (TOKENS * 2)
#define OFF_PROB  (TOKENS * 4)

__global__ __launch_bounds__(256, 2)
void router_fused(const float* __restrict__ x,
                  const float* __restrict__ W1,
                  const float* __restrict__ b1,
                  const float* __restrict__ W2,
                  const float* __restrict__ b2,
                  float* __restrict__ out)
{
    __shared__ float xs[BM][XS_LD];     // x tile   [m][k]
    __shared__ float ws[BK][BN];        // W1 tile  [k][n]
    __shared__ float hs[BM][HS_LD];     // relu(h)  [m][n]
    __shared__ float w2s[BN * NEXP];    // W2 chunk [n][e] flat
    __shared__ float ls[BM][NEXP];      // logits

    const int tid = threadIdx.x;
    const int tx  = tid & 15;    // n-quad (phase A), expert (phase B)
    const int ty  = tid >> 4;    // m-quad (phase A), token-group (phase B)
    const int m0  = blockIdx.x * BM;

    // phase-B logit accumulators: token = ty + 16*j, expert = tx
    float lacc[4] = {0.f, 0.f, 0.f, 0.f};

    for (int nc = 0; nc < DHID / BN; ++nc) {
        const int nb = nc * BN;
        float acc[4][4];
        #pragma unroll
        for (int i = 0; i < 4; ++i)
            #pragma unroll
            for (int j = 0; j < 4; ++j) acc[i][j] = 0.f;

        for (int kc = 0; kc < DMODEL / BK; ++kc) {
            const int kb = kc * BK;
            __syncthreads();   // protect xs/ws from previous iteration's readers
            // ---- stage x[64 tok][64 k] and W1[64 k][64 n], float4, coalesced ----
            #pragma unroll
            for (int r = 0; r < 4; ++r) {
                const int row = ty + r * 16;
                const float4 xv = *(const float4*)(x  + (size_t)(m0 + row) * DMODEL + kb + tx * 4);
                *(float4*)(&xs[row][tx * 4]) = xv;
                const float4 wv = *(const float4*)(W1 + (size_t)(kb + row) * DHID  + nb + tx * 4);
                *(float4*)(&ws[row][tx * 4]) = wv;
            }
            __syncthreads();
            // ---- 64x64x64 fp32 tile: 4x4 per thread, b128 LDS reads ----
            #pragma unroll
            for (int k4 = 0; k4 < BK / 4; ++k4) {
                float4 xv[4], wv[4];
                #pragma unroll
                for (int q = 0; q < 4; ++q)
                    xv[q] = *(const float4*)(&xs[ty * 4 + q][k4 * 4]);
                #pragma unroll
                for (int q = 0; q < 4; ++q)
                    wv[q] = *(const float4*)(&ws[k4 * 4 + q][tx * 4]);
                #pragma unroll
                for (int mi = 0; mi < 4; ++mi) {
                    const float* xp = (const float*)(&xv[mi]);
                    #pragma unroll
                    for (int kk = 0; kk < 4; ++kk) {
                        const float a = xp[kk];
                        acc[mi][0] = fmaf(a, wv[kk].x, acc[mi][0]);
                        acc[mi][1] = fmaf(a, wv[kk].y, acc[mi][1]);
                        acc[mi][2] = fmaf(a, wv[kk].z, acc[mi][2]);
                        acc[mi][3] = fmaf(a, wv[kk].w, acc[mi][3]);
                    }
                }
            }
        }

        // ---- epilogue: +b1, ReLU -> hs; stage W2 chunk ----
        // (hs/w2s readers from previous nc finished long ago: many barriers since)
        const float4 b1v = *(const float4*)(b1 + nb + tx * 4);
        #pragma unroll
        for (int mi = 0; mi < 4; ++mi) {
            float4 h;
            h.x = fmaxf(acc[mi][0] + b1v.x, 0.f);
            h.y = fmaxf(acc[mi][1] + b1v.y, 0.f);
            h.z = fmaxf(acc[mi][2] + b1v.z, 0.f);
            h.w = fmaxf(acc[mi][3] + b1v.w, 0.f);
            *(float4*)(&hs[ty * 4 + mi][tx * 4]) = h;
        }
        // W2 chunk [nb..nb+64)x16 is contiguous: 1024 floats, 4 per thread
        {
            const float4 v = *(const float4*)(W2 + (size_t)nb * NEXP + tid * 4);
            *(float4*)(&w2s[tid * 4]) = v;
        }
        __syncthreads();

        // ---- phase B: logits[t][e] += sum_n hs[t][n] * W2[n][e] ----
        #pragma unroll
        for (int j = 0; j < 4; ++j) {
            const int t = ty + 16 * j;
            float a = lacc[j];
            #pragma unroll
            for (int nq = 0; nq < 16; ++nq) {
                const float4 hv = *(const float4*)(&hs[t][nq * 4]);
                a = fmaf(hv.x, w2s[(nq * 4 + 0) * NEXP + tx], a);
                a = fmaf(hv.y, w2s[(nq * 4 + 1) * NEXP + tx], a);
                a = fmaf(hv.z, w2s[(nq * 4 + 2) * NEXP + tx], a);
                a = fmaf(hv.w, w2s[(nq * 4 + 3) * NEXP + tx], a);
            }
            lacc[j] = a;
        }
        // next nc's first __syncthreads protects hs/w2s
    }

    // ---- write logits to LDS ----
    #pragma unroll
    for (int j = 0; j < 4; ++j)
        ls[ty + 16 * j][tx] = lacc[j];
    __syncthreads();

    // ---- softmax + top-2 (one thread per token) ----
    if (tid < BM) {
        const int t = tid;
        float l[NEXP];
        float mx = -1e30f;
        #pragma unroll
        for (int i = 0; i < NEXP; ++i) {
            l[i] = ls[t][i] + b2[i];
            mx = fmaxf(mx, l[i]);
        }
        float p[NEXP];
        float s = 0.f;
        #pragma unroll
        for (int i = 0; i < NEXP; ++i) { p[i] = __expf(l[i] - mx) ; s += p[i]; }
        // use precise expf to track numpy closely
        s = 0.f;
        #pragma unroll
        for (int i = 0; i < NEXP; ++i) { p[i] = expf(l[i] - mx); s += p[i]; }
        const float inv = 1.f / s;
        #pragma unroll
        for (int i = 0; i < NEXP; ++i) p[i] *= inv;

        // top-2, strict '>' ascending => lowest index on ties (matches lax.top_k)
        int i1 = 0; float p1 = p[0];
        #pragma unroll
        for (int i = 1; i < NEXP; ++i) { if (p[i] > p1) { p1 = p[i]; i1 = i; } }
        int i2 = -1; float p2 = -1.f;
        #pragma unroll
        for (int i = 0; i < NEXP; ++i) {
            if (i != i1 && p[i] > p2) { p2 = p[i]; i2 = i; }
        }
        const float denom = p1 + p2 + 1e-8f;
        const size_t gt = (size_t)(m0 + t);
        out[gt * 2 + 0] = p1 / denom;
        out[gt * 2 + 1] = p2 / denom;
        out[OFF_IDX + gt * 2 + 0] = (float)i1;
        out[OFF_IDX + gt * 2 + 1] = (float)i2;
        #pragma unroll
        for (int i = 0; i < NEXP; ++i) out[OFF_PROB + gt * 16 + i] = p[i];
    }
}

extern "C" void kernel_launch(void* const* d_in, const int* in_sizes, int n_in,
                              void* d_out, int out_size, void* d_ws, size_t ws_size,
                              hipStream_t stream) {
    const float* x  = (const float*)d_in[0];
    const float* W1 = (const float*)d_in[1];
    const float* b1 = (const float*)d_in[2];
    const float* W2 = (const float*)d_in[3];
    const float* b2 = (const float*)d_in[4];
    float* out = (float*)d_out;

    dim3 grid(TOKENS / BM);   // 512 blocks, 2 per CU
    dim3 block(256);
    hipLaunchKernelGGL(router_fused, grid, block, 0, stream, x, W1, b1, W2, b2, out);
}